// Round 9
// baseline (275.273 us; speedup 1.0000x reference)
//
#include <hip/hip_runtime.h>

#define GRIDW 48
#define NNODES 147456
#define NTILES 2304   // NNODES/64
#define GB 512        // persistent GEMM grid

typedef __attribute__((ext_vector_type(8))) short short8;
typedef __attribute__((ext_vector_type(4))) float f32x4;

__device__ inline unsigned short f2bf(float f) {
    union { float f; unsigned u; } v; v.f = f;
    unsigned r = v.u + 0x7FFFu + ((v.u >> 16) & 1u);
    return (unsigned short)(r >> 16);
}
__device__ inline float bf2f(unsigned short h) {
    union { unsigned u; float f; } v; v.u = ((unsigned)h) << 16;
    return v.f;
}

// ---------------------------------------------------------------------------
// prep: weights->bf16 [col][KP] (k-contig, zero-padded), padded biases,
// zero stats. wt2 is 192 cols: [t0|t1|t2|r] each 48 wide (pad cols zero).
// ---------------------------------------------------------------------------
__global__ void prep(const float* __restrict__ w0, const float* __restrict__ b0,
                     const float* __restrict__ w1, const float* __restrict__ b1,
                     const float* __restrict__ g2, const float* __restrict__ w2,
                     const float* __restrict__ b2, const float* __restrict__ w3,
                     const float* __restrict__ b3,
                     unsigned short* __restrict__ wt0, unsigned short* __restrict__ wt1,
                     unsigned short* __restrict__ wt2, unsigned short* __restrict__ wt3,
                     float* __restrict__ biasf0, float* __restrict__ biasf1,
                     float* __restrict__ biasf2, float* __restrict__ biasf3,
                     float* __restrict__ statz) {
    int id = blockIdx.x * 256 + threadIdx.x;
    if (id < 14336) {                         // wt0: 112 cols x 128 k
        int col = id >> 7, k = id & 127;
        wt0[id] = (col < 102) ? f2bf(w0[k * 102 + col]) : (unsigned short)0;
    } else if (id < 24576) {                  // wt1: 80 x 128
        int e = id - 14336; int col = e >> 7, k = e & 127;
        wt1[e] = (col < 73 && k < 102) ? f2bf(w1[k * 73 + col]) : (unsigned short)0;
    } else if (id < 43008) {                  // wt2: 192 x 96
        int e = id - 24576; int col = e / 96, k = e - (e / 96) * 96;
        int blk = col / 48, c = col - blk * 48;
        unsigned short v = 0;
        if (k < 73 && c < 44)
            v = (blk < 3) ? f2bf(g2[k * 132 + blk * 44 + c]) : f2bf(w2[k * 44 + c]);
        wt2[e] = v;
    } else if (id < 44032) {                  // wt3: 16 x 64
        int e = id - 43008; int col = e >> 6, k = e & 63;
        wt3[e] = (k < 44) ? f2bf(w3[k * 16 + col]) : (unsigned short)0;
    } else if (id < 44144) { int c = id - 44032; biasf0[c] = (c < 102) ? b0[c] : 0.f; }
    else if (id < 44224) { int c = id - 44144; biasf1[c] = (c < 73) ? b1[c] : 0.f; }
    else if (id < 44416) { int c = id - 44224; int blk = c / 48, cc = c - blk * 48;
                           biasf2[c] = (blk == 3 && cc < 44) ? b2[cc] : 0.f; }
    else if (id < 44432) { int c = id - 44416; biasf3[c] = b3[c]; }
    else if (id < 44944) { statz[id - 44432] = 0.f; }
}

// ---------------------------------------------------------------------------
// Persistent MFMA GEMM (unchanged from round 7/8): whole-K in LDS, 64-row
// tiles grid-strided, double-buffered A with register prefetch, BN of the
// previous layer applied on the A side during LDS commit.
// ---------------------------------------------------------------------------
template<int K, int KP, int MP, int MOUT, int PREVM, int BNSRC,
         bool STATS, bool OUTBF, bool ABF16>
__global__ __launch_bounds__(256) void gemm_p(
    const void* __restrict__ Ain, const unsigned short* __restrict__ WT,
    const float* __restrict__ biasf,
    const float* __restrict__ q0, const float* __restrict__ q1,
    const float* __restrict__ q2, const float* __restrict__ q3,
    float invN, void* __restrict__ Yout,
    float* __restrict__ sumO, float* __restrict__ ssO)
{
    constexpr int KS = KP + 8;
    constexpr int NCF = MP / 16;
    constexpr int UPR = ABF16 ? (K / 8) : (K / 4);
    constexpr int TOT = 64 * UPR;
    constexpr int NLD = (TOT + 255) / 256;
    __shared__ __align__(16) unsigned short As[2][64 * KS];
    __shared__ __align__(16) unsigned short Bs[MP * KS];
    __shared__ float bnA[KP], bnB[KP];

    const int tid = threadIdx.x;
    const int lane = tid & 63, wv = tid >> 6, qd = lane >> 4, lc = lane & 15;

    if (BNSRC == 1) {
        if (tid < KP) {
            float a = 0.f, b = 0.f;
            if (tid < PREVM) {
                float m = q0[tid] * invN;
                float v = q1[tid] * invN - m * m;
                float sc = q2[tid] * rsqrtf(v + 1e-5f);
                a = sc; b = q3[tid] - m * sc;
            }
            bnA[tid] = a; bnB[tid] = b;
        }
    } else if (BNSRC == 2) {
        if (tid < KP) {
            bnA[tid] = (tid < PREVM) ? q0[tid] : 0.f;
            bnB[tid] = (tid < PREVM) ? q1[tid] : 0.f;
        }
    }
    for (int g = tid; g < MP * (KP / 8); g += 256) {
        int col = g / (KP / 8), u = g - col * (KP / 8);
        *(uint4*)&Bs[col * KS + u * 8] = *(const uint4*)&WT[(size_t)col * KP + u * 8];
    }
    if constexpr (KP > K) {
        constexpr int PADU = (KP - K) / 2;
        for (int g = tid; g < 64 * PADU; g += 256) {
            int row = g / PADU, u = g - row * PADU;
            *(unsigned*)&As[0][row * KS + K + u * 2] = 0u;
            *(unsigned*)&As[1][row * KS + K + u * 2] = 0u;
        }
    }

    float bvr[NCF];
#pragma unroll
    for (int cf = 0; cf < NCF; ++cf) bvr[cf] = biasf[cf * 16 + lc];

    float cs[NCF], cq[NCF];
    if (STATS) {
#pragma unroll
        for (int cf = 0; cf < NCF; ++cf) { cs[cf] = 0.f; cq[cf] = 0.f; }
    }

    uint4 pfb[NLD];
    float4 pff[NLD];

    int t = blockIdx.x;
#pragma unroll
    for (int i = 0; i < NLD; ++i) {
        int g = tid + 256 * i;
        if (g < TOT) {
            if constexpr (ABF16)
                pfb[i] = *(const uint4*)((const unsigned short*)Ain + (size_t)t * 64 * K + g * 8);
            else
                pff[i] = *(const float4*)((const float*)Ain + (size_t)t * 64 * K + g * 4);
        }
    }
    __syncthreads();

    int buf = 0;
    for (; t < NTILES; t += GB) {
#pragma unroll
        for (int i = 0; i < NLD; ++i) {
            int g = tid + 256 * i;
            if (g < TOT) {
                int row = g / UPR, u = g - row * UPR;
                if constexpr (ABF16) {
                    uint4 w = pfb[i];
                    if (BNSRC != 0) {
                        unsigned* wp = (unsigned*)&w;
#pragma unroll
                        for (int pp = 0; pp < 4; ++pp) {
                            int kk = u * 8 + 2 * pp;
                            float lo = bf2f((unsigned short)(wp[pp] & 0xFFFFu)) * bnA[kk] + bnB[kk];
                            float hi = bf2f((unsigned short)(wp[pp] >> 16)) * bnA[kk + 1] + bnB[kk + 1];
                            wp[pp] = (unsigned)f2bf(lo) | ((unsigned)f2bf(hi) << 16);
                        }
                    }
                    *(uint4*)&As[buf][row * KS + u * 8] = w;
                } else {
                    float4 v = pff[i];
                    if (BNSRC != 0) {
                        int kk = u * 4;
                        v.x = v.x * bnA[kk] + bnB[kk];
                        v.y = v.y * bnA[kk + 1] + bnB[kk + 1];
                        v.z = v.z * bnA[kk + 2] + bnB[kk + 2];
                        v.w = v.w * bnA[kk + 3] + bnB[kk + 3];
                    }
                    unsigned lo = (unsigned)f2bf(v.x) | ((unsigned)f2bf(v.y) << 16);
                    unsigned hi = (unsigned)f2bf(v.z) | ((unsigned)f2bf(v.w) << 16);
                    *(uint2*)&As[buf][row * KS + u * 4] = make_uint2(lo, hi);
                }
            }
        }
        int t2 = t + GB;
        if (t2 < NTILES) {
#pragma unroll
            for (int i = 0; i < NLD; ++i) {
                int g = tid + 256 * i;
                if (g < TOT) {
                    if constexpr (ABF16)
                        pfb[i] = *(const uint4*)((const unsigned short*)Ain + (size_t)t2 * 64 * K + g * 8);
                    else
                        pff[i] = *(const float4*)((const float*)Ain + (size_t)t2 * 64 * K + g * 4);
                }
            }
        }
        __syncthreads();

        f32x4 acc[NCF];
#pragma unroll
        for (int cf = 0; cf < NCF; ++cf) acc[cf] = (f32x4){0.f, 0.f, 0.f, 0.f};
#pragma unroll
        for (int kt = 0; kt < KP / 32; ++kt) {
            const int kb = kt * 32 + qd * 8;
            short8 a = *(const short8*)&As[buf][(wv * 16 + lc) * KS + kb];
#pragma unroll
            for (int cf = 0; cf < NCF; ++cf) {
                short8 b = *(const short8*)&Bs[(cf * 16 + lc) * KS + kb];
                acc[cf] = __builtin_amdgcn_mfma_f32_16x16x32_bf16(a, b, acc[cf], 0, 0, 0);
            }
        }
#pragma unroll
        for (int cf = 0; cf < NCF; ++cf) {
            const int col = cf * 16 + lc;
            const float bv = bvr[cf];
#pragma unroll
            for (int rr = 0; rr < 4; ++rr) {
                float v = acc[cf][rr] + bv;
                int row = t * 64 + wv * 16 + qd * 4 + rr;
                if (OUTBF) ((unsigned short*)Yout)[(size_t)row * MP + col] = f2bf(v);
                else       ((float*)Yout)[(size_t)row * MP + col] = v;
                if (STATS) { cs[cf] += v; cq[cf] += v * v; }
            }
        }
        buf ^= 1;
    }

    if (STATS) {
        __syncthreads();
        float* red = (float*)As;
        float* redq = red + 4 * MP;
#pragma unroll
        for (int cf = 0; cf < NCF; ++cf) {
            float s = cs[cf], qq = cq[cf];
            s += __shfl_down(s, 32, 64); s += __shfl_down(s, 16, 64);
            qq += __shfl_down(qq, 32, 64); qq += __shfl_down(qq, 16, 64);
            if (lane < 16) {
                red[wv * MP + cf * 16 + lane] = s;
                redq[wv * MP + cf * 16 + lane] = qq;
            }
        }
        __syncthreads();
        if (tid < MOUT) {
            float s = red[tid] + red[MP + tid] + red[2 * MP + tid] + red[3 * MP + tid];
            float qq = redq[tid] + redq[MP + tid] + redq[2 * MP + tid] + redq[3 * MP + tid];
            atomicAdd(&sumO[tid], s);
            atomicAdd(&ssO[tid], qq);
        }
    }
}

// ---------------------------------------------------------------------------
// GMM stencil v3: TR is N x 192 bf16 ([t0|t1|t2|r] x 48, pad cols zero).
// Block = (batch, 3-row band): 1024 blocks, 4 blocks/CU, 16 waves/CU.
// XCD swizzle keeps all 16 bands of a batch on one XCD. Thread og8 = tid%6
// constant -> 8-col register stats; all loads are 16B uint4.
// C out: bf16 N x 48 (pad cols auto-zero since t/r pads are zero).
// ---------------------------------------------------------------------------
__device__ inline void fma8(const unsigned short* __restrict__ p, float g, float* acc) {
    uint4 v = *(const uint4*)p;
    unsigned w[4] = {v.x, v.y, v.z, v.w};
#pragma unroll
    for (int j = 0; j < 4; ++j) {
        acc[2 * j]     += g * bf2f((unsigned short)(w[j] & 0xFFFFu));
        acc[2 * j + 1] += g * bf2f((unsigned short)(w[j] >> 16));
    }
}

__global__ __launch_bounds__(256, 4) void gmm_stencil(
    const unsigned short* __restrict__ TR, unsigned short* __restrict__ C,
    const float* __restrict__ mu, const float* __restrict__ sigma,
    float* __restrict__ sum2, float* __restrict__ ss2)
{
    __shared__ float gs[9][3];
    __shared__ float red[96];
    const int tid = threadIdx.x;
    if (tid < 96) red[tid] = 0.f;
    if (tid < 27) {
        int d = tid / 3, k = tid - (tid / 3) * 3;
        int dx = d / 3 - 1, dy = d % 3 - 1;
        float ex = 0.5f * dx + 0.5f, ey = 0.5f * dy + 0.5f;
        float mx = mu[k * 2], my = mu[k * 2 + 1];
        float sx = sigma[k * 2], sy = sigma[k * 2 + 1];
        gs[d][k] = expf(-0.5f * ((ex - mx) * (ex - mx) / (1e-15f + sx * sx) +
                                 (ey - my) * (ey - my) / (1e-15f + sy * sy)));
    }
    __syncthreads();

    // XCD-aware: blocks with equal blk%8 (one XCD under round-robin) cover
    // all 16 bands of 8 consecutive batches.
    const int r = blockIdx.x & 7;
    const int m = blockIdx.x >> 3;
    const int batch = r * 8 + (m >> 4);
    const int band = m & 15;
    const int base = batch * 2304 + band * 144;

    const int og8 = tid % 6;
    const int ln0 = tid / 6;
    const int c0 = og8 * 8;

    float s8[8] = {0, 0, 0, 0, 0, 0, 0, 0};
    float q8[8] = {0, 0, 0, 0, 0, 0, 0, 0};

    if (tid < 252) {
#pragma unroll
        for (int i = 0; i < 4; ++i) {
            int ln = ln0 + 42 * i;
            if (ln >= 144) break;
            int node = base + ln;
            int rx = ln / 48, iy = ln - rx * 48;
            int ix = band * 3 + rx;
            float acc[8] = {0, 0, 0, 0, 0, 0, 0, 0};
#pragma unroll
            for (int dx = -1; dx <= 1; ++dx) {
                int jx = ix + dx;
                if (jx < 0 || jx >= GRIDW) continue;
#pragma unroll
                for (int dy = -1; dy <= 1; ++dy) {
                    int jy = iy + dy;
                    if (jy < 0 || jy >= GRIDW) continue;
                    int d = (dx + 1) * 3 + (dy + 1);
                    const unsigned short* tj = TR + (size_t)(node + dx * GRIDW + dy) * 192 + c0;
                    fma8(tj,      gs[d][0], acc);
                    fma8(tj + 48, gs[d][1], acc);
                    fma8(tj + 96, gs[d][2], acc);
                }
            }
            int cnt = ((ix > 0) + (ix < GRIDW - 1) + 1) * ((iy > 0) + (iy < GRIDW - 1) + 1);
            float inv = 1.f / (float)cnt;
            uint4 rv = *(const uint4*)(TR + (size_t)node * 192 + 144 + c0);
            unsigned rw[4] = {rv.x, rv.y, rv.z, rv.w};
            float o[8];
#pragma unroll
            for (int j = 0; j < 4; ++j) {
                o[2 * j]     = acc[2 * j] * inv + bf2f((unsigned short)(rw[j] & 0xFFFFu));
                o[2 * j + 1] = acc[2 * j + 1] * inv + bf2f((unsigned short)(rw[j] >> 16));
            }
            uint4 ov;
            unsigned* op = (unsigned*)&ov;
#pragma unroll
            for (int j = 0; j < 4; ++j)
                op[j] = (unsigned)f2bf(o[2 * j]) | ((unsigned)f2bf(o[2 * j + 1]) << 16);
            *(uint4*)&C[(size_t)node * 48 + c0] = ov;
#pragma unroll
            for (int j = 0; j < 8; ++j) { s8[j] += o[j]; q8[j] += o[j] * o[j]; }
        }
    }
#pragma unroll
    for (int j = 0; j < 8; ++j) {
        atomicAdd(&red[c0 + j], s8[j]);
        atomicAdd(&red[48 + c0 + j], q8[j]);
    }
    __syncthreads();
    if (tid < 44) atomicAdd(&sum2[tid], red[tid]);
    else if (tid >= 48 && tid < 92) atomicAdd(&ss2[tid - 48], red[tid]);
}

// ---------------------------------------------------------------------------
extern "C" void kernel_launch(void* const* d_in, const int* in_sizes, int n_in,
                              void* d_out, int out_size, void* d_ws, size_t ws_size,
                              hipStream_t stream) {
    const float* x      = (const float*)d_in[0];
    const float* w0     = (const float*)d_in[3];
    const float* b0     = (const float*)d_in[4];
    const float* gamma0 = (const float*)d_in[5];
    const float* beta0  = (const float*)d_in[6];
    const float* w1     = (const float*)d_in[7];
    const float* b1     = (const float*)d_in[8];
    const float* gamma1 = (const float*)d_in[9];
    const float* beta1  = (const float*)d_in[10];
    const float* w2     = (const float*)d_in[11];
    const float* g2     = (const float*)d_in[12];
    const float* mu2    = (const float*)d_in[13];
    const float* sigma2 = (const float*)d_in[14];
    const float* b2     = (const float*)d_in[15];
    const float* gamma2 = (const float*)d_in[16];
    const float* beta2  = (const float*)d_in[17];
    const float* w3     = (const float*)d_in[18];
    const float* b3     = (const float*)d_in[19];
    float* out = (float*)d_out;

    const int N = NNODES;
    const float invN = 1.0f / (float)N;

    // [0,44N): Y1 bf16 (40N f-eq) then C bf16 48 cols (24N f-eq) — disjoint
    // [44N,140N): Y0 bf16 (56N f-eq) then TR bf16 192 cols (96N f-eq) — disjoint
    const size_t tailOff = (size_t)N * 140;
    size_t need = (tailOff + 48000) * sizeof(float);
    if (ws_size < need) return;

    float* ws = (float*)d_ws;
    unsigned short* bufY1 = (unsigned short*)ws;
    unsigned short* bufC  = (unsigned short*)ws;
    unsigned short* bufY0 = (unsigned short*)(ws + (size_t)N * 44);
    unsigned short* bufTR = bufY0;

    float* tail = ws + tailOff;
    float* sum0 = tail;            // 112
    float* ss0  = tail + 112;      // 112
    float* sum1 = tail + 224;      // 80
    float* ss1  = tail + 304;      // 80
    float* sum2 = tail + 384;      // 44
    float* ss2  = tail + 448;      // 44
    float* biasf0 = tail + 512;    // 112
    float* biasf1 = tail + 624;    // 80
    float* biasf2 = tail + 704;    // 192
    float* biasf3 = tail + 896;    // 16
    unsigned short* wt0 = (unsigned short*)(tail + 912);    // 112*128
    unsigned short* wt1 = wt0 + 14336;                      // 80*128
    unsigned short* wt2 = wt1 + 10240;                      // 192*96
    unsigned short* wt3 = wt2 + 18432;                      // 16*64

    prep<<<176, 256, 0, stream>>>(w0, b0, w1, b1, g2, w2, b2, w3, b3,
                                  wt0, wt1, wt2, wt3,
                                  biasf0, biasf1, biasf2, biasf3, tail);

    // L0: Y0 = x @ w0 + b0 (bf16 out, stats fused)
    gemm_p<128, 128, 112, 102, 0, 0, true, true, false><<<GB, 256, 0, stream>>>(
        x, wt0, biasf0, nullptr, nullptr, nullptr, nullptr, invN, bufY0, sum0, ss0);

    // L1: Y1 = BN0(Y0) @ w1 + b1 (BN on A-side; stats fused)
    gemm_p<112, 128, 80, 73, 102, 1, true, true, true><<<GB, 256, 0, stream>>>(
        bufY0, wt1, biasf1, sum0, ss0, gamma0, beta0, invN, bufY1, sum1, ss1);

    // L2: TR = BN1(Y1) @ [t0|t1|t2|r] (192 wide, pad cols zero)
    gemm_p<80, 96, 192, 192, 73, 1, false, true, true><<<GB, 256, 0, stream>>>(
        bufY1, wt2, biasf2, sum1, ss1, gamma1, beta1, invN, bufTR, nullptr, nullptr);

    // stencil: C(bf16,48) = r + agg(t)/deg ; BN2 stats direct to sum2/ss2
    gmm_stencil<<<1024, 256, 0, stream>>>(bufTR, bufC, mu2, sigma2, sum2, ss2);

    // L3: out = BN2(C) @ w3 + b3 (fp32 out; BN fold from sums; pad cols inert)
    gemm_p<48, 64, 16, 16, 44, 1, false, false, true><<<GB, 256, 0, stream>>>(
        bufC, wt3, biasf3, sum2, ss2, gamma2, beta2, invN, out, nullptr, nullptr);
}

// Round 10
// 272.279 us; speedup vs baseline: 1.0110x; 1.0110x over previous
//
#include <hip/hip_runtime.h>

#define GRIDW 48
#define NNODES 147456
#define NTILES 2304   // NNODES/64
#define GB 512        // persistent GEMM grid

typedef __attribute__((ext_vector_type(8))) short short8;
typedef __attribute__((ext_vector_type(4))) float f32x4;

__device__ inline unsigned short f2bf(float f) {
    union { float f; unsigned u; } v; v.f = f;
    unsigned r = v.u + 0x7FFFu + ((v.u >> 16) & 1u);
    return (unsigned short)(r >> 16);
}
__device__ inline float bf2f(unsigned short h) {
    union { unsigned u; float f; } v; v.u = ((unsigned)h) << 16;
    return v.f;
}

// ---------------------------------------------------------------------------
// prep: weights->bf16 [col][KP] (k-contig, zero-padded), padded biases,
// zero stats (512 floats). wt2 is 176 cols: [g2(132) | w2(44)].
// ---------------------------------------------------------------------------
__global__ void prep(const float* __restrict__ w0, const float* __restrict__ b0,
                     const float* __restrict__ w1, const float* __restrict__ b1,
                     const float* __restrict__ g2, const float* __restrict__ w2,
                     const float* __restrict__ b2, const float* __restrict__ w3,
                     const float* __restrict__ b3,
                     unsigned short* __restrict__ wt0, unsigned short* __restrict__ wt1,
                     unsigned short* __restrict__ wt2, unsigned short* __restrict__ wt3,
                     float* __restrict__ biasf0, float* __restrict__ biasf1,
                     float* __restrict__ biasf2, float* __restrict__ biasf3,
                     float* __restrict__ statz) {
    int id = blockIdx.x * 256 + threadIdx.x;
    if (id < 14336) {                         // wt0: 112 cols x 128 k
        int col = id >> 7, k = id & 127;
        wt0[id] = (col < 102) ? f2bf(w0[k * 102 + col]) : (unsigned short)0;
    } else if (id < 24576) {                  // wt1: 80 x 128
        int e = id - 14336; int col = e >> 7, k = e & 127;
        wt1[e] = (col < 73 && k < 102) ? f2bf(w1[k * 73 + col]) : (unsigned short)0;
    } else if (id < 41472) {                  // wt2: 176 x 96 (g2 | w2)
        int e = id - 24576; int col = e / 96, k = e - (e / 96) * 96;
        unsigned short v = 0;
        if (k < 73) v = (col < 132) ? f2bf(g2[k * 132 + col]) : f2bf(w2[k * 44 + (col - 132)]);
        wt2[e] = v;
    } else if (id < 42496) {                  // wt3: 16 x 64
        int e = id - 41472; int col = e >> 6, k = e & 63;
        wt3[e] = (k < 44) ? f2bf(w3[k * 16 + col]) : (unsigned short)0;
    } else if (id < 42608) { int c = id - 42496; biasf0[c] = (c < 102) ? b0[c] : 0.f; }
    else if (id < 42688) { int c = id - 42608; biasf1[c] = (c < 73) ? b1[c] : 0.f; }
    else if (id < 42864) { int c = id - 42688; biasf2[c] = (c < 132) ? 0.f : b2[c - 132]; }
    else if (id < 42880) { int c = id - 42864; biasf3[c] = b3[c]; }
    else if (id < 43392) { statz[id - 42880] = 0.f; }
}

// ---------------------------------------------------------------------------
// Persistent MFMA GEMM (proven in rounds 7-9): whole-K in LDS, 64-row tiles
// grid-strided, double-buffered A with register prefetch, BN of the previous
// layer applied on the A side during LDS commit.
// ---------------------------------------------------------------------------
template<int K, int KP, int MP, int MOUT, int PREVM, int BNSRC,
         bool STATS, bool OUTBF, bool ABF16>
__global__ __launch_bounds__(256) void gemm_p(
    const void* __restrict__ Ain, const unsigned short* __restrict__ WT,
    const float* __restrict__ biasf,
    const float* __restrict__ q0, const float* __restrict__ q1,
    const float* __restrict__ q2, const float* __restrict__ q3,
    float invN, void* __restrict__ Yout,
    float* __restrict__ sumO, float* __restrict__ ssO)
{
    constexpr int KS = KP + 8;
    constexpr int NCF = MP / 16;
    constexpr int UPR = ABF16 ? (K / 8) : (K / 4);
    constexpr int TOT = 64 * UPR;
    constexpr int NLD = (TOT + 255) / 256;
    __shared__ __align__(16) unsigned short As[2][64 * KS];
    __shared__ __align__(16) unsigned short Bs[MP * KS];
    __shared__ float bnA[KP], bnB[KP];

    const int tid = threadIdx.x;
    const int lane = tid & 63, wv = tid >> 6, qd = lane >> 4, lc = lane & 15;

    if (BNSRC == 1) {
        if (tid < KP) {
            float a = 0.f, b = 0.f;
            if (tid < PREVM) {
                float m = q0[tid] * invN;
                float v = q1[tid] * invN - m * m;
                float sc = q2[tid] * rsqrtf(v + 1e-5f);
                a = sc; b = q3[tid] - m * sc;
            }
            bnA[tid] = a; bnB[tid] = b;
        }
    } else if (BNSRC == 2) {
        if (tid < KP) {
            bnA[tid] = (tid < PREVM) ? q0[tid] : 0.f;
            bnB[tid] = (tid < PREVM) ? q1[tid] : 0.f;
        }
    }
    for (int g = tid; g < MP * (KP / 8); g += 256) {
        int col = g / (KP / 8), u = g - col * (KP / 8);
        *(uint4*)&Bs[col * KS + u * 8] = *(const uint4*)&WT[(size_t)col * KP + u * 8];
    }
    if constexpr (KP > K) {
        constexpr int PADU = (KP - K) / 2;
        for (int g = tid; g < 64 * PADU; g += 256) {
            int row = g / PADU, u = g - row * PADU;
            *(unsigned*)&As[0][row * KS + K + u * 2] = 0u;
            *(unsigned*)&As[1][row * KS + K + u * 2] = 0u;
        }
    }

    float bvr[NCF];
#pragma unroll
    for (int cf = 0; cf < NCF; ++cf) bvr[cf] = biasf[cf * 16 + lc];

    float cs[NCF], cq[NCF];
    if (STATS) {
#pragma unroll
        for (int cf = 0; cf < NCF; ++cf) { cs[cf] = 0.f; cq[cf] = 0.f; }
    }

    uint4 pfb[NLD];
    float4 pff[NLD];

    int t = blockIdx.x;
#pragma unroll
    for (int i = 0; i < NLD; ++i) {
        int g = tid + 256 * i;
        if (g < TOT) {
            if constexpr (ABF16)
                pfb[i] = *(const uint4*)((const unsigned short*)Ain + (size_t)t * 64 * K + g * 8);
            else
                pff[i] = *(const float4*)((const float*)Ain + (size_t)t * 64 * K + g * 4);
        }
    }
    __syncthreads();

    int buf = 0;
    for (; t < NTILES; t += GB) {
#pragma unroll
        for (int i = 0; i < NLD; ++i) {
            int g = tid + 256 * i;
            if (g < TOT) {
                int row = g / UPR, u = g - row * UPR;
                if constexpr (ABF16) {
                    uint4 w = pfb[i];
                    if (BNSRC != 0) {
                        unsigned* wp = (unsigned*)&w;
#pragma unroll
                        for (int pp = 0; pp < 4; ++pp) {
                            int kk = u * 8 + 2 * pp;
                            float lo = bf2f((unsigned short)(wp[pp] & 0xFFFFu)) * bnA[kk] + bnB[kk];
                            float hi = bf2f((unsigned short)(wp[pp] >> 16)) * bnA[kk + 1] + bnB[kk + 1];
                            wp[pp] = (unsigned)f2bf(lo) | ((unsigned)f2bf(hi) << 16);
                        }
                    }
                    *(uint4*)&As[buf][row * KS + u * 8] = w;
                } else {
                    float4 v = pff[i];
                    if (BNSRC != 0) {
                        int kk = u * 4;
                        v.x = v.x * bnA[kk] + bnB[kk];
                        v.y = v.y * bnA[kk + 1] + bnB[kk + 1];
                        v.z = v.z * bnA[kk + 2] + bnB[kk + 2];
                        v.w = v.w * bnA[kk + 3] + bnB[kk + 3];
                    }
                    unsigned lo = (unsigned)f2bf(v.x) | ((unsigned)f2bf(v.y) << 16);
                    unsigned hi = (unsigned)f2bf(v.z) | ((unsigned)f2bf(v.w) << 16);
                    *(uint2*)&As[buf][row * KS + u * 4] = make_uint2(lo, hi);
                }
            }
        }
        int t2 = t + GB;
        if (t2 < NTILES) {
#pragma unroll
            for (int i = 0; i < NLD; ++i) {
                int g = tid + 256 * i;
                if (g < TOT) {
                    if constexpr (ABF16)
                        pfb[i] = *(const uint4*)((const unsigned short*)Ain + (size_t)t2 * 64 * K + g * 8);
                    else
                        pff[i] = *(const float4*)((const float*)Ain + (size_t)t2 * 64 * K + g * 4);
                }
            }
        }
        __syncthreads();

        f32x4 acc[NCF];
#pragma unroll
        for (int cf = 0; cf < NCF; ++cf) acc[cf] = (f32x4){0.f, 0.f, 0.f, 0.f};
#pragma unroll
        for (int kt = 0; kt < KP / 32; ++kt) {
            const int kb = kt * 32 + qd * 8;
            short8 a = *(const short8*)&As[buf][(wv * 16 + lc) * KS + kb];
#pragma unroll
            for (int cf = 0; cf < NCF; ++cf) {
                short8 b = *(const short8*)&Bs[(cf * 16 + lc) * KS + kb];
                acc[cf] = __builtin_amdgcn_mfma_f32_16x16x32_bf16(a, b, acc[cf], 0, 0, 0);
            }
        }
#pragma unroll
        for (int cf = 0; cf < NCF; ++cf) {
            const int col = cf * 16 + lc;
            const float bv = bvr[cf];
#pragma unroll
            for (int rr = 0; rr < 4; ++rr) {
                float v = acc[cf][rr] + bv;
                int row = t * 64 + wv * 16 + qd * 4 + rr;
                if (OUTBF) ((unsigned short*)Yout)[(size_t)row * MP + col] = f2bf(v);
                else       ((float*)Yout)[(size_t)row * MP + col] = v;
                if (STATS) { cs[cf] += v; cq[cf] += v * v; }
            }
        }
        buf ^= 1;
    }

    if (STATS) {
        __syncthreads();
        float* red = (float*)As;
        float* redq = red + 4 * MP;
#pragma unroll
        for (int cf = 0; cf < NCF; ++cf) {
            float s = cs[cf], qq = cq[cf];
            s += __shfl_down(s, 32, 64); s += __shfl_down(s, 16, 64);
            qq += __shfl_down(qq, 32, 64); qq += __shfl_down(qq, 16, 64);
            if (lane < 16) {
                red[wv * MP + cf * 16 + lane] = s;
                redq[wv * MP + cf * 16 + lane] = qq;
            }
        }
        __syncthreads();
        if (tid < MOUT) {
            float s = red[tid] + red[MP + tid] + red[2 * MP + tid] + red[3 * MP + tid];
            float qq = redq[tid] + redq[MP + tid] + redq[2 * MP + tid] + redq[3 * MP + tid];
            atomicAdd(&sumO[tid], s);
            atomicAdd(&ssO[tid], qq);
        }
    }
}

// ---------------------------------------------------------------------------
// Separable GMM stencil: gauss[dx,dy,k] = gx[dx,k]*gy[dy,k] (exact — exp of
// a sum over coords). Per node-row compute u[k][4] = sum_dy gy*t (9 uint2
// loads), keep 3-row rolling window in registers, combine with gx.
// 9 loads/node-group instead of 28; logical L2/L3 volume cut ~3x.
// Block = (batch, 3-row x-seg), 1024 blocks, XCD swizzle (batch -> one XCD).
// ---------------------------------------------------------------------------
__device__ inline void load_u(const unsigned short* __restrict__ TR, int b,
                              int jx, int iy, int c0, const float (*gy)[3],
                              float* __restrict__ u) {
#pragma unroll
    for (int j = 0; j < 12; ++j) u[j] = 0.f;
    if (jx < 0 || jx >= GRIDW) return;
    const unsigned short* rowp = TR + (size_t)(b * 2304 + jx * 48) * 176;
#pragma unroll
    for (int dy = -1; dy <= 1; ++dy) {
        int jy = iy + dy;
        if (jy < 0 || jy >= GRIDW) continue;
        const unsigned short* np = rowp + (size_t)jy * 176 + c0;
#pragma unroll
        for (int k = 0; k < 3; ++k) {
            uint2 v = *(const uint2*)(np + k * 44);
            float g = gy[dy + 1][k];
            u[k * 4 + 0] += g * bf2f((unsigned short)(v.x & 0xFFFFu));
            u[k * 4 + 1] += g * bf2f((unsigned short)(v.x >> 16));
            u[k * 4 + 2] += g * bf2f((unsigned short)(v.y & 0xFFFFu));
            u[k * 4 + 3] += g * bf2f((unsigned short)(v.y >> 16));
        }
    }
}

__global__ __launch_bounds__(256) void gmm_stencil(
    const unsigned short* __restrict__ TR, unsigned short* __restrict__ C,
    const float* __restrict__ mu, const float* __restrict__ sigma,
    float* __restrict__ sum2, float* __restrict__ ss2)
{
    __shared__ float gx[3][3], gy[3][3];   // [d][k]
    __shared__ float red[88];
    const int tid = threadIdx.x;
    if (tid < 88) red[tid] = 0.f;
    if (tid < 18) {
        int d = (tid / 3) % 3, k = tid % 3;
        bool isy = tid >= 9;
        float e = 0.5f * (float)(d - 1) + 0.5f;
        float mm = mu[k * 2 + (isy ? 1 : 0)];
        float sg = sigma[k * 2 + (isy ? 1 : 0)];
        float v = expf(-0.5f * (e - mm) * (e - mm) / (1e-15f + sg * sg));
        if (isy) gy[d][k] = v; else gx[d][k] = v;
    }
    __syncthreads();

    // XCD swizzle: blocks with equal blk%8 (one XCD under round-robin) cover
    // all 16 segs of 8 consecutive batches.
    const int r = blockIdx.x & 7;
    const int m = blockIdx.x >> 3;
    const int b = r * 8 + (m >> 4);
    const int x0 = (m & 15) * 3;

    for (int p = 0; p < 3; ++p) {
        int idx = tid + 256 * p;
        if (idx >= 528) break;               // 48 iy x 11 og
        int og = idx % 11, iy = idx / 11;
        int c0 = og * 4;
        float u0[12], u1[12], u2[12];
        load_u(TR, b, x0 - 1, iy, c0, gy, u0);
        load_u(TR, b, x0,     iy, c0, gy, u1);
        float s4[4] = {0, 0, 0, 0}, q4[4] = {0, 0, 0, 0};
        int ny = 1 + (iy > 0) + (iy < GRIDW - 1);
#pragma unroll
        for (int st = 0; st < 3; ++st) {
            int ix = x0 + st;
            float* ua = (st == 0) ? u0 : ((st == 1) ? u1 : u2);
            float* ub = (st == 0) ? u1 : ((st == 1) ? u2 : u0);
            float* uc = (st == 0) ? u2 : ((st == 1) ? u0 : u1);
            load_u(TR, b, ix + 1, iy, c0, gy, uc);
            int nx = 1 + (ix > 0) + (ix < GRIDW - 1);
            float inv = 1.f / (float)(nx * ny);
            int node = b * 2304 + ix * 48 + iy;
            uint2 rv = *(const uint2*)(TR + (size_t)node * 176 + 132 + c0);
            float o[4];
#pragma unroll
            for (int j = 0; j < 4; ++j) {
                float acc = 0.f;
#pragma unroll
                for (int k = 0; k < 3; ++k)
                    acc += gx[0][k] * ua[k * 4 + j] + gx[1][k] * ub[k * 4 + j]
                         + gx[2][k] * uc[k * 4 + j];
                o[j] = acc * inv;
            }
            o[0] += bf2f((unsigned short)(rv.x & 0xFFFFu));
            o[1] += bf2f((unsigned short)(rv.x >> 16));
            o[2] += bf2f((unsigned short)(rv.y & 0xFFFFu));
            o[3] += bf2f((unsigned short)(rv.y >> 16));
            unsigned lo = (unsigned)f2bf(o[0]) | ((unsigned)f2bf(o[1]) << 16);
            unsigned hi = (unsigned)f2bf(o[2]) | ((unsigned)f2bf(o[3]) << 16);
            *(uint2*)&C[(size_t)node * 48 + c0] = make_uint2(lo, hi);
            if (og == 10)   // zero pad cols 44..47
                *(uint2*)&C[(size_t)node * 48 + 44] = make_uint2(0u, 0u);
#pragma unroll
            for (int j = 0; j < 4; ++j) { s4[j] += o[j]; q4[j] += o[j] * o[j]; }
        }
#pragma unroll
        for (int j = 0; j < 4; ++j) {
            atomicAdd(&red[c0 + j], s4[j]);
            atomicAdd(&red[44 + c0 + j], q4[j]);
        }
    }
    __syncthreads();
    if (tid < 44) atomicAdd(&sum2[tid], red[tid]);
    else if (tid < 88) atomicAdd(&ss2[tid - 44], red[tid]);
}

// ---------------------------------------------------------------------------
extern "C" void kernel_launch(void* const* d_in, const int* in_sizes, int n_in,
                              void* d_out, int out_size, void* d_ws, size_t ws_size,
                              hipStream_t stream) {
    const float* x      = (const float*)d_in[0];
    const float* w0     = (const float*)d_in[3];
    const float* b0     = (const float*)d_in[4];
    const float* gamma0 = (const float*)d_in[5];
    const float* beta0  = (const float*)d_in[6];
    const float* w1     = (const float*)d_in[7];
    const float* b1     = (const float*)d_in[8];
    const float* gamma1 = (const float*)d_in[9];
    const float* beta1  = (const float*)d_in[10];
    const float* w2     = (const float*)d_in[11];
    const float* g2     = (const float*)d_in[12];
    const float* mu2    = (const float*)d_in[13];
    const float* sigma2 = (const float*)d_in[14];
    const float* b2     = (const float*)d_in[15];
    const float* gamma2 = (const float*)d_in[16];
    const float* beta2  = (const float*)d_in[17];
    const float* w3     = (const float*)d_in[18];
    const float* b3     = (const float*)d_in[19];
    float* out = (float*)d_out;

    const int N = NNODES;
    const float invN = 1.0f / (float)N;

    // [0,44N): Y1 bf16 (40N f-eq) then C bf16 48 cols (24N f-eq) — disjoint
    // [44N,132N): Y0 bf16 (56N f-eq) then TR bf16 176 cols (88N f-eq) — disjoint
    const size_t tailOff = (size_t)N * 132;
    size_t need = (tailOff + 48000) * sizeof(float);
    if (ws_size < need) return;

    float* ws = (float*)d_ws;
    unsigned short* bufY1 = (unsigned short*)ws;
    unsigned short* bufC  = (unsigned short*)ws;
    unsigned short* bufY0 = (unsigned short*)(ws + (size_t)N * 44);
    unsigned short* bufTR = bufY0;

    float* tail = ws + tailOff;
    float* sum0 = tail;            // 112
    float* ss0  = tail + 112;      // 112
    float* sum1 = tail + 224;      // 80
    float* ss1  = tail + 304;      // 80
    float* sum2 = tail + 384;      // 44
    float* ss2  = tail + 448;      // 44
    float* biasf0 = tail + 512;    // 112
    float* biasf1 = tail + 624;    // 80
    float* biasf2 = tail + 704;    // 176
    float* biasf3 = tail + 880;    // 16
    unsigned short* wt0 = (unsigned short*)(tail + 896);    // 112*128
    unsigned short* wt1 = wt0 + 14336;                      // 80*128
    unsigned short* wt2 = wt1 + 10240;                      // 176*96
    unsigned short* wt3 = wt2 + 16896;                      // 16*64

    prep<<<170, 256, 0, stream>>>(w0, b0, w1, b1, g2, w2, b2, w3, b3,
                                  wt0, wt1, wt2, wt3,
                                  biasf0, biasf1, biasf2, biasf3, tail);

    // L0: Y0 = x @ w0 + b0 (bf16 out, stats fused)
    gemm_p<128, 128, 112, 102, 0, 0, true, true, false><<<GB, 256, 0, stream>>>(
        x, wt0, biasf0, nullptr, nullptr, nullptr, nullptr, invN, bufY0, sum0, ss0);

    // L1: Y1 = BN0(Y0) @ w1 + b1 (BN on A-side; stats fused)
    gemm_p<112, 128, 80, 73, 102, 1, true, true, true><<<GB, 256, 0, stream>>>(
        bufY0, wt1, biasf1, sum0, ss0, gamma0, beta0, invN, bufY1, sum1, ss1);

    // L2: TR = BN1(Y1) @ [g2 | w2] (+[0|b2]), 176 wide
    gemm_p<80, 96, 176, 176, 73, 1, false, true, true><<<GB, 256, 0, stream>>>(
        bufY1, wt2, biasf2, sum1, ss1, gamma1, beta1, invN, bufTR, nullptr, nullptr);

    // separable stencil: C(bf16,48) = r + agg(t)/deg ; BN2 stats to sum2/ss2
    gmm_stencil<<<1024, 256, 0, stream>>>(bufTR, bufC, mu2, sigma2, sum2, ss2);

    // L3: out = BN2(C) @ w3 + b3 (fp32 out; BN fold from sums; pad cols inert)
    gemm_p<48, 64, 16, 16, 44, 1, false, false, true><<<GB, 256, 0, stream>>>(
        bufC, wt3, biasf3, sum2, ss2, gamma2, beta2, invN, out, nullptr, nullptr);
}

// Round 11
// 252.226 us; speedup vs baseline: 1.0914x; 1.0795x over previous
//
#include <hip/hip_runtime.h>

#define GRIDW 48
#define NNODES 147456
#define NTILES 2304   // NNODES/64
#define GB 512        // persistent GEMM grid

typedef __attribute__((ext_vector_type(8))) short short8;
typedef __attribute__((ext_vector_type(4))) float f32x4;

__device__ inline unsigned short f2bf(float f) {
    union { float f; unsigned u; } v; v.f = f;
    unsigned r = v.u + 0x7FFFu + ((v.u >> 16) & 1u);
    return (unsigned short)(r >> 16);
}
__device__ inline float bf2f(unsigned short h) {
    union { unsigned u; float f; } v; v.u = ((unsigned)h) << 16;
    return v.f;
}

// ---------------------------------------------------------------------------
// prep: weights->bf16 [col][KP] (k-contig, zero-padded), padded biases,
// zero stats. wt2 is 176 cols: [g2(132) | w2(44)].
// ---------------------------------------------------------------------------
__global__ void prep(const float* __restrict__ w0, const float* __restrict__ b0,
                     const float* __restrict__ w1, const float* __restrict__ b1,
                     const float* __restrict__ g2, const float* __restrict__ w2,
                     const float* __restrict__ b2, const float* __restrict__ w3,
                     const float* __restrict__ b3,
                     unsigned short* __restrict__ wt0, unsigned short* __restrict__ wt1,
                     unsigned short* __restrict__ wt2, unsigned short* __restrict__ wt3,
                     float* __restrict__ biasf0, float* __restrict__ biasf1,
                     float* __restrict__ biasf2, float* __restrict__ biasf3,
                     float* __restrict__ statz) {
    int id = blockIdx.x * 256 + threadIdx.x;
    if (id < 14336) {                         // wt0: 112 cols x 128 k
        int col = id >> 7, k = id & 127;
        wt0[id] = (col < 102) ? f2bf(w0[k * 102 + col]) : (unsigned short)0;
    } else if (id < 24576) {                  // wt1: 80 x 128
        int e = id - 14336; int col = e >> 7, k = e & 127;
        wt1[e] = (col < 73 && k < 102) ? f2bf(w1[k * 73 + col]) : (unsigned short)0;
    } else if (id < 41472) {                  // wt2: 176 x 96 (g2 | w2)
        int e = id - 24576; int col = e / 96, k = e - (e / 96) * 96;
        unsigned short v = 0;
        if (k < 73) v = (col < 132) ? f2bf(g2[k * 132 + col]) : f2bf(w2[k * 44 + (col - 132)]);
        wt2[e] = v;
    } else if (id < 42496) {                  // wt3: 16 x 64
        int e = id - 41472; int col = e >> 6, k = e & 63;
        wt3[e] = (k < 44) ? f2bf(w3[k * 16 + col]) : (unsigned short)0;
    } else if (id < 42608) { int c = id - 42496; biasf0[c] = (c < 102) ? b0[c] : 0.f; }
    else if (id < 42688) { int c = id - 42608; biasf1[c] = (c < 73) ? b1[c] : 0.f; }
    else if (id < 42864) { int c = id - 42688; biasf2[c] = (c < 132) ? 0.f : b2[c - 132]; }
    else if (id < 42880) { int c = id - 42864; biasf3[c] = b3[c]; }
    else if (id < 43392) { statz[id - 42880] = 0.f; }
}

// ---------------------------------------------------------------------------
// reduce_stats: one block per column; sums P per-block partials (layout:
// partial[p][2*M] = [sums(M) | sqs(M)]) into sum[col]/ss[col]. No atomics.
// ---------------------------------------------------------------------------
__global__ __launch_bounds__(128) void reduce_stats(
    const float* __restrict__ partial, float* __restrict__ sum,
    float* __restrict__ ss, int M, int P)
{
    const int col = blockIdx.x;
    const int half = threadIdx.x >> 6;     // 0: sum, 1: sumsq
    const int lane = threadIdx.x & 63;
    const float* src = partial + col + half * M;
    float s = 0.f;
    for (int p = lane; p < P; p += 64) s += src[(size_t)p * 2 * M];
    s += __shfl_down(s, 32); s += __shfl_down(s, 16); s += __shfl_down(s, 8);
    s += __shfl_down(s, 4);  s += __shfl_down(s, 2);  s += __shfl_down(s, 1);
    if (lane == 0) { if (half) ss[col] = s; else sum[col] = s; }
}

// ---------------------------------------------------------------------------
// Persistent MFMA GEMM (rounds 7-10): whole-K in LDS, 64-row tiles
// grid-strided, double-buffered A with register prefetch, BN of the previous
// layer applied on the A side during LDS commit. STATS now writes a
// contention-free per-block partial slice (no global atomics).
// ---------------------------------------------------------------------------
template<int K, int KP, int MP, int MOUT, int PREVM, int BNSRC,
         bool STATS, bool OUTBF, bool ABF16>
__global__ __launch_bounds__(256) void gemm_p(
    const void* __restrict__ Ain, const unsigned short* __restrict__ WT,
    const float* __restrict__ biasf,
    const float* __restrict__ q0, const float* __restrict__ q1,
    const float* __restrict__ q2, const float* __restrict__ q3,
    float invN, void* __restrict__ Yout, float* __restrict__ partial)
{
    constexpr int KS = KP + 8;
    constexpr int NCF = MP / 16;
    constexpr int UPR = ABF16 ? (K / 8) : (K / 4);
    constexpr int TOT = 64 * UPR;
    constexpr int NLD = (TOT + 255) / 256;
    __shared__ __align__(16) unsigned short As[2][64 * KS];
    __shared__ __align__(16) unsigned short Bs[MP * KS];
    __shared__ float bnA[KP], bnB[KP];

    const int tid = threadIdx.x;
    const int lane = tid & 63, wv = tid >> 6, qd = lane >> 4, lc = lane & 15;

    if (BNSRC == 1) {
        if (tid < KP) {
            float a = 0.f, b = 0.f;
            if (tid < PREVM) {
                float m = q0[tid] * invN;
                float v = q1[tid] * invN - m * m;
                float sc = q2[tid] * rsqrtf(v + 1e-5f);
                a = sc; b = q3[tid] - m * sc;
            }
            bnA[tid] = a; bnB[tid] = b;
        }
    } else if (BNSRC == 2) {
        if (tid < KP) {
            bnA[tid] = (tid < PREVM) ? q0[tid] : 0.f;
            bnB[tid] = (tid < PREVM) ? q1[tid] : 0.f;
        }
    }
    for (int g = tid; g < MP * (KP / 8); g += 256) {
        int col = g / (KP / 8), u = g - col * (KP / 8);
        *(uint4*)&Bs[col * KS + u * 8] = *(const uint4*)&WT[(size_t)col * KP + u * 8];
    }
    if constexpr (KP > K) {
        constexpr int PADU = (KP - K) / 2;
        for (int g = tid; g < 64 * PADU; g += 256) {
            int row = g / PADU, u = g - row * PADU;
            *(unsigned*)&As[0][row * KS + K + u * 2] = 0u;
            *(unsigned*)&As[1][row * KS + K + u * 2] = 0u;
        }
    }

    float bvr[NCF];
#pragma unroll
    for (int cf = 0; cf < NCF; ++cf) bvr[cf] = biasf[cf * 16 + lc];

    float cs[NCF], cq[NCF];
    if (STATS) {
#pragma unroll
        for (int cf = 0; cf < NCF; ++cf) { cs[cf] = 0.f; cq[cf] = 0.f; }
    }

    uint4 pfb[NLD];
    float4 pff[NLD];

    int t = blockIdx.x;
#pragma unroll
    for (int i = 0; i < NLD; ++i) {
        int g = tid + 256 * i;
        if (g < TOT) {
            if constexpr (ABF16)
                pfb[i] = *(const uint4*)((const unsigned short*)Ain + (size_t)t * 64 * K + g * 8);
            else
                pff[i] = *(const float4*)((const float*)Ain + (size_t)t * 64 * K + g * 4);
        }
    }
    __syncthreads();

    int buf = 0;
    for (; t < NTILES; t += GB) {
#pragma unroll
        for (int i = 0; i < NLD; ++i) {
            int g = tid + 256 * i;
            if (g < TOT) {
                int row = g / UPR, u = g - row * UPR;
                if constexpr (ABF16) {
                    uint4 w = pfb[i];
                    if (BNSRC != 0) {
                        unsigned* wp = (unsigned*)&w;
#pragma unroll
                        for (int pp = 0; pp < 4; ++pp) {
                            int kk = u * 8 + 2 * pp;
                            float lo = bf2f((unsigned short)(wp[pp] & 0xFFFFu)) * bnA[kk] + bnB[kk];
                            float hi = bf2f((unsigned short)(wp[pp] >> 16)) * bnA[kk + 1] + bnB[kk + 1];
                            wp[pp] = (unsigned)f2bf(lo) | ((unsigned)f2bf(hi) << 16);
                        }
                    }
                    *(uint4*)&As[buf][row * KS + u * 8] = w;
                } else {
                    float4 v = pff[i];
                    if (BNSRC != 0) {
                        int kk = u * 4;
                        v.x = v.x * bnA[kk] + bnB[kk];
                        v.y = v.y * bnA[kk + 1] + bnB[kk + 1];
                        v.z = v.z * bnA[kk + 2] + bnB[kk + 2];
                        v.w = v.w * bnA[kk + 3] + bnB[kk + 3];
                    }
                    unsigned lo = (unsigned)f2bf(v.x) | ((unsigned)f2bf(v.y) << 16);
                    unsigned hi = (unsigned)f2bf(v.z) | ((unsigned)f2bf(v.w) << 16);
                    *(uint2*)&As[buf][row * KS + u * 4] = make_uint2(lo, hi);
                }
            }
        }
        int t2 = t + GB;
        if (t2 < NTILES) {
#pragma unroll
            for (int i = 0; i < NLD; ++i) {
                int g = tid + 256 * i;
                if (g < TOT) {
                    if constexpr (ABF16)
                        pfb[i] = *(const uint4*)((const unsigned short*)Ain + (size_t)t2 * 64 * K + g * 8);
                    else
                        pff[i] = *(const float4*)((const float*)Ain + (size_t)t2 * 64 * K + g * 4);
                }
            }
        }
        __syncthreads();

        f32x4 acc[NCF];
#pragma unroll
        for (int cf = 0; cf < NCF; ++cf) acc[cf] = (f32x4){0.f, 0.f, 0.f, 0.f};
#pragma unroll
        for (int kt = 0; kt < KP / 32; ++kt) {
            const int kb = kt * 32 + qd * 8;
            short8 a = *(const short8*)&As[buf][(wv * 16 + lc) * KS + kb];
#pragma unroll
            for (int cf = 0; cf < NCF; ++cf) {
                short8 b = *(const short8*)&Bs[(cf * 16 + lc) * KS + kb];
                acc[cf] = __builtin_amdgcn_mfma_f32_16x16x32_bf16(a, b, acc[cf], 0, 0, 0);
            }
        }
#pragma unroll
        for (int cf = 0; cf < NCF; ++cf) {
            const int col = cf * 16 + lc;
            const float bv = bvr[cf];
#pragma unroll
            for (int rr = 0; rr < 4; ++rr) {
                float v = acc[cf][rr] + bv;
                int row = t * 64 + wv * 16 + qd * 4 + rr;
                if (OUTBF) ((unsigned short*)Yout)[(size_t)row * MP + col] = f2bf(v);
                else       ((float*)Yout)[(size_t)row * MP + col] = v;
                if (STATS) { cs[cf] += v; cq[cf] += v * v; }
            }
        }
        buf ^= 1;
    }

    if (STATS) {
        __syncthreads();
        float* red = (float*)As;
        float* redq = red + 4 * MP;
#pragma unroll
        for (int cf = 0; cf < NCF; ++cf) {
            float s = cs[cf], qq = cq[cf];
            s += __shfl_down(s, 32, 64); s += __shfl_down(s, 16, 64);
            qq += __shfl_down(qq, 32, 64); qq += __shfl_down(qq, 16, 64);
            if (lane < 16) {
                red[wv * MP + cf * 16 + lane] = s;
                redq[wv * MP + cf * 16 + lane] = qq;
            }
        }
        __syncthreads();
        if (tid < MOUT) {
            float s = red[tid] + red[MP + tid] + red[2 * MP + tid] + red[3 * MP + tid];
            float qq = redq[tid] + redq[MP + tid] + redq[2 * MP + tid] + redq[3 * MP + tid];
            // contention-free per-block slice; reduced by reduce_stats
            partial[(size_t)blockIdx.x * (2 * MOUT) + tid] = s;
            partial[(size_t)blockIdx.x * (2 * MOUT) + MOUT + tid] = qq;
        }
    }
}

// ---------------------------------------------------------------------------
// Separable GMM stencil (round 10): gauss = gx*gy exactly; rolling 3-row
// window of y-combined u in registers; 9 uint2 loads per node-group.
// Stats now exit via per-block partial slice (no global atomics).
// ---------------------------------------------------------------------------
__device__ inline void load_u(const unsigned short* __restrict__ TR, int b,
                              int jx, int iy, int c0, const float (*gy)[3],
                              float* __restrict__ u) {
#pragma unroll
    for (int j = 0; j < 12; ++j) u[j] = 0.f;
    if (jx < 0 || jx >= GRIDW) return;
    const unsigned short* rowp = TR + (size_t)(b * 2304 + jx * 48) * 176;
#pragma unroll
    for (int dy = -1; dy <= 1; ++dy) {
        int jy = iy + dy;
        if (jy < 0 || jy >= GRIDW) continue;
        const unsigned short* np = rowp + (size_t)jy * 176 + c0;
#pragma unroll
        for (int k = 0; k < 3; ++k) {
            uint2 v = *(const uint2*)(np + k * 44);
            float g = gy[dy + 1][k];
            u[k * 4 + 0] += g * bf2f((unsigned short)(v.x & 0xFFFFu));
            u[k * 4 + 1] += g * bf2f((unsigned short)(v.x >> 16));
            u[k * 4 + 2] += g * bf2f((unsigned short)(v.y & 0xFFFFu));
            u[k * 4 + 3] += g * bf2f((unsigned short)(v.y >> 16));
        }
    }
}

__global__ __launch_bounds__(256) void gmm_stencil(
    const unsigned short* __restrict__ TR, unsigned short* __restrict__ C,
    const float* __restrict__ mu, const float* __restrict__ sigma,
    float* __restrict__ partial)
{
    __shared__ float gx[3][3], gy[3][3];   // [d][k]
    __shared__ float red[88];
    const int tid = threadIdx.x;
    if (tid < 88) red[tid] = 0.f;
    if (tid < 18) {
        int d = (tid / 3) % 3, k = tid % 3;
        bool isy = tid >= 9;
        float e = 0.5f * (float)(d - 1) + 0.5f;
        float mm = mu[k * 2 + (isy ? 1 : 0)];
        float sg = sigma[k * 2 + (isy ? 1 : 0)];
        float v = expf(-0.5f * (e - mm) * (e - mm) / (1e-15f + sg * sg));
        if (isy) gy[d][k] = v; else gx[d][k] = v;
    }
    __syncthreads();

    const int r = blockIdx.x & 7;
    const int m = blockIdx.x >> 3;
    const int b = r * 8 + (m >> 4);
    const int x0 = (m & 15) * 3;

    for (int p = 0; p < 3; ++p) {
        int idx = tid + 256 * p;
        if (idx >= 528) break;               // 48 iy x 11 og
        int og = idx % 11, iy = idx / 11;
        int c0 = og * 4;
        float u0[12], u1[12], u2[12];
        load_u(TR, b, x0 - 1, iy, c0, gy, u0);
        load_u(TR, b, x0,     iy, c0, gy, u1);
        float s4[4] = {0, 0, 0, 0}, q4[4] = {0, 0, 0, 0};
        int ny = 1 + (iy > 0) + (iy < GRIDW - 1);
#pragma unroll
        for (int st = 0; st < 3; ++st) {
            int ix = x0 + st;
            float* ua = (st == 0) ? u0 : ((st == 1) ? u1 : u2);
            float* ub = (st == 0) ? u1 : ((st == 1) ? u2 : u0);
            float* uc = (st == 0) ? u2 : ((st == 1) ? u0 : u1);
            load_u(TR, b, ix + 1, iy, c0, gy, uc);
            int nx = 1 + (ix > 0) + (ix < GRIDW - 1);
            float inv = 1.f / (float)(nx * ny);
            int node = b * 2304 + ix * 48 + iy;
            uint2 rv = *(const uint2*)(TR + (size_t)node * 176 + 132 + c0);
            float o[4];
#pragma unroll
            for (int j = 0; j < 4; ++j) {
                float acc = 0.f;
#pragma unroll
                for (int k = 0; k < 3; ++k)
                    acc += gx[0][k] * ua[k * 4 + j] + gx[1][k] * ub[k * 4 + j]
                         + gx[2][k] * uc[k * 4 + j];
                o[j] = acc * inv;
            }
            o[0] += bf2f((unsigned short)(rv.x & 0xFFFFu));
            o[1] += bf2f((unsigned short)(rv.x >> 16));
            o[2] += bf2f((unsigned short)(rv.y & 0xFFFFu));
            o[3] += bf2f((unsigned short)(rv.y >> 16));
            unsigned lo = (unsigned)f2bf(o[0]) | ((unsigned)f2bf(o[1]) << 16);
            unsigned hi = (unsigned)f2bf(o[2]) | ((unsigned)f2bf(o[3]) << 16);
            *(uint2*)&C[(size_t)node * 48 + c0] = make_uint2(lo, hi);
            if (og == 10)   // zero pad cols 44..47
                *(uint2*)&C[(size_t)node * 48 + 44] = make_uint2(0u, 0u);
#pragma unroll
            for (int j = 0; j < 4; ++j) { s4[j] += o[j]; q4[j] += o[j] * o[j]; }
        }
#pragma unroll
        for (int j = 0; j < 4; ++j) {
            atomicAdd(&red[c0 + j], s4[j]);
            atomicAdd(&red[44 + c0 + j], q4[j]);
        }
    }
    __syncthreads();
    if (tid < 88) partial[(size_t)blockIdx.x * 88 + tid] = red[tid];
}

// ---------------------------------------------------------------------------
extern "C" void kernel_launch(void* const* d_in, const int* in_sizes, int n_in,
                              void* d_out, int out_size, void* d_ws, size_t ws_size,
                              hipStream_t stream) {
    const float* x      = (const float*)d_in[0];
    const float* w0     = (const float*)d_in[3];
    const float* b0     = (const float*)d_in[4];
    const float* gamma0 = (const float*)d_in[5];
    const float* beta0  = (const float*)d_in[6];
    const float* w1     = (const float*)d_in[7];
    const float* b1     = (const float*)d_in[8];
    const float* gamma1 = (const float*)d_in[9];
    const float* beta1  = (const float*)d_in[10];
    const float* w2     = (const float*)d_in[11];
    const float* g2     = (const float*)d_in[12];
    const float* mu2    = (const float*)d_in[13];
    const float* sigma2 = (const float*)d_in[14];
    const float* b2     = (const float*)d_in[15];
    const float* gamma2 = (const float*)d_in[16];
    const float* beta2  = (const float*)d_in[17];
    const float* w3     = (const float*)d_in[18];
    const float* b3     = (const float*)d_in[19];
    float* out = (float*)d_out;

    const int N = NNODES;
    const float invN = 1.0f / (float)N;

    // [0,44N): Y1 bf16 (40N f-eq) then C bf16 48 cols (24N f-eq) — disjoint
    // [44N,132N): Y0 bf16 (56N f-eq) then TR bf16 176 cols (88N f-eq) — disjoint
    const size_t tailOff = (size_t)N * 132;
    size_t need = (tailOff + 300000) * sizeof(float);
    if (ws_size < need) return;

    float* ws = (float*)d_ws;
    unsigned short* bufY1 = (unsigned short*)ws;
    unsigned short* bufC  = (unsigned short*)ws;
    unsigned short* bufY0 = (unsigned short*)(ws + (size_t)N * 44);
    unsigned short* bufTR = bufY0;

    float* tail = ws + tailOff;
    float* sum0 = tail;            // 112
    float* ss0  = tail + 112;      // 112
    float* sum1 = tail + 224;      // 80
    float* ss1  = tail + 304;      // 80
    float* sum2 = tail + 384;      // 44
    float* ss2  = tail + 448;      // 44
    float* biasf0 = tail + 512;    // 112
    float* biasf1 = tail + 624;    // 80
    float* biasf2 = tail + 704;    // 176
    float* biasf3 = tail + 880;    // 16
    unsigned short* wt0 = (unsigned short*)(tail + 896);    // 112*128
    unsigned short* wt1 = wt0 + 14336;                      // 80*128
    unsigned short* wt2 = wt1 + 10240;                      // 176*96
    unsigned short* wt3 = wt2 + 16896;                      // 16*64
    float* partG0 = tail + 22400;            // 512 x 204 = 104448
    float* partG1 = partG0 + 104448;         // 512 x 146 = 74752
    float* partS  = partG1 + 74752;          // 1024 x 88 = 90112

    prep<<<170, 256, 0, stream>>>(w0, b0, w1, b1, g2, w2, b2, w3, b3,
                                  wt0, wt1, wt2, wt3,
                                  biasf0, biasf1, biasf2, biasf3, tail);

    // L0: Y0 = x @ w0 + b0 (bf16 out, stats -> partials)
    gemm_p<128, 128, 112, 102, 0, 0, true, true, false><<<GB, 256, 0, stream>>>(
        x, wt0, biasf0, nullptr, nullptr, nullptr, nullptr, invN, bufY0, partG0);
    reduce_stats<<<102, 128, 0, stream>>>(partG0, sum0, ss0, 102, GB);

    // L1: Y1 = BN0(Y0) @ w1 + b1 (BN on A-side; stats -> partials)
    gemm_p<112, 128, 80, 73, 102, 1, true, true, true><<<GB, 256, 0, stream>>>(
        bufY0, wt1, biasf1, sum0, ss0, gamma0, beta0, invN, bufY1, partG1);
    reduce_stats<<<73, 128, 0, stream>>>(partG1, sum1, ss1, 73, GB);

    // L2: TR = BN1(Y1) @ [g2 | w2] (+[0|b2]), 176 wide
    gemm_p<80, 96, 176, 176, 73, 1, false, true, true><<<GB, 256, 0, stream>>>(
        bufY1, wt2, biasf2, sum1, ss1, gamma1, beta1, invN, bufTR, nullptr);

    // separable stencil: C(bf16,48) = r + agg(t)/deg ; stats -> partials
    gmm_stencil<<<1024, 256, 0, stream>>>(bufTR, bufC, mu2, sigma2, partS);
    reduce_stats<<<44, 128, 0, stream>>>(partS, sum2, ss2, 44, 1024);

    // L3: out = BN2(C) @ w3 + b3 (fp32 out; BN fold from sums; pad cols inert)
    gemm_p<48, 64, 16, 16, 44, 1, false, false, true><<<GB, 256, 0, stream>>>(
        bufC, wt3, biasf3, sum2, ss2, gamma2, beta2, invN, out, nullptr);
}